// Round 4
// baseline (410.317 us; speedup 1.0000x reference)
//
#include <hip/hip_runtime.h>

#define NGROUPS  1024
#define EPSF     1e-9f
#define MAX_ITERS 30
#define SUM_MASK ((1ull << 49) - 1)
#define CNT_SHIFT 49
#define FIX_SCALE 1073741824.0f      // 2^30
#define FIX_INV   (1.0 / 1073741824.0)
#define SBLK 512                     // k_stats block size
#define STILE 4                      // float4 tiles per thread

typedef float vfloat4 __attribute__((ext_vector_type(4)));

// ---- monotone float<->uint mapping for atomicMin/Max on floats ----
__device__ __forceinline__ unsigned enc_f(float f) {
    unsigned u = __float_as_uint(f);
    return (u & 0x80000000u) ? ~u : (u | 0x80000000u);
}
__device__ __forceinline__ float dec_f(unsigned e) {
    unsigned u = (e & 0x80000000u) ? (e ^ 0x80000000u) : ~e;
    return __uint_as_float(u);
}

// ---- kernel 0: init gpack + done counter (ws poisoned 0xAA each launch) ----
__global__ __launch_bounds__(NGROUPS) void k_init(unsigned long long* gpack,
                                                  unsigned* done) {
    int g = threadIdx.x;
    gpack[g] = 0ull;
    if (g == 0) *done = 0u;
}

// ---- kernel A: stream once; write y_clipped; packed (cnt|sum) histogram.
// Last finishing block runs the per-group phase (feasibility, T, scan). ----
template <bool EXACT>
__global__ __launch_bounds__(SBLK) void k_stats(const float4* __restrict__ yraw4,
                                                const float4* __restrict__ yreal4,
                                                const int4*   __restrict__ gid4,
                                                float4*       __restrict__ out4,
                                                unsigned long long* gpack,
                                                unsigned* done,
                                                unsigned* feas, float* gT,
                                                unsigned* gmn, unsigned* gmx,
                                                unsigned* gbase, unsigned* gcur,
                                                unsigned* total, int n4) {
    __shared__ unsigned long long s_pk[NGROUPS];
    int t = threadIdx.x;
    s_pk[t] = 0ull; s_pk[t + SBLK] = 0ull;
    __syncthreads();

    int base = blockIdx.x * (SBLK * STILE) + t;
    float4 yr[STILE], ye[STILE];
    int4   gg[STILE];
    if (EXACT) {
        // unconditional loads -> compiler hoists all 12 into flight (MLP)
#pragma unroll
        for (int k = 0; k < STILE; ++k) yr[k] = yraw4[base + k * SBLK];
#pragma unroll
        for (int k = 0; k < STILE; ++k) ye[k] = yreal4[base + k * SBLK];
#pragma unroll
        for (int k = 0; k < STILE; ++k) gg[k] = gid4[base + k * SBLK];
#pragma unroll
        for (int k = 0; k < STILE; ++k) {
            float yrs[4] = { yr[k].x, yr[k].y, yr[k].z, yr[k].w };
            float yes[4] = { ye[k].x, ye[k].y, ye[k].z, ye[k].w };
            int   gs[4]  = { gg[k].x, gg[k].y, gg[k].z, gg[k].w };
            float oc[4];
#pragma unroll
            for (int j = 0; j < 4; ++j) {
                float yraw = yrs[j];
                float yrc  = fmaxf(yes[j], EPSF);
                float l = 0.9f * yrc;
                float u = 1.1f * yrc;
                float yclip = fminf(fmaxf(yraw, l), u);
                oc[j] = yclip;
                float s = yclip / yrc;                    // in [0.9, 1.1]
                unsigned long long pk = (1ull << CNT_SHIFT)
                    + (unsigned long long)__float2uint_rn(s * FIX_SCALE);
                atomicAdd(&s_pk[gs[j]], pk);
            }
            vfloat4 ov = { oc[0], oc[1], oc[2], oc[3] };
            __builtin_nontemporal_store(ov, (vfloat4*)&out4[base + k * SBLK]);
        }
    } else {
#pragma unroll
        for (int k = 0; k < STILE; ++k) {
            int i = base + k * SBLK;
            if (i >= n4) continue;
            float4 a = yraw4[i], b = yreal4[i];
            int4 g4 = gid4[i];
            float yrs[4] = { a.x, a.y, a.z, a.w };
            float yes[4] = { b.x, b.y, b.z, b.w };
            int   gs[4]  = { g4.x, g4.y, g4.z, g4.w };
            float oc[4];
#pragma unroll
            for (int j = 0; j < 4; ++j) {
                float yrc  = fmaxf(yes[j], EPSF);
                float l = 0.9f * yrc, u = 1.1f * yrc;
                float yclip = fminf(fmaxf(yrs[j], l), u);
                oc[j] = yclip;
                unsigned long long pk = (1ull << CNT_SHIFT)
                    + (unsigned long long)__float2uint_rn((yclip / yrc) * FIX_SCALE);
                atomicAdd(&s_pk[gs[j]], pk);
            }
            out4[i] = make_float4(oc[0], oc[1], oc[2], oc[3]);
        }
    }
    __syncthreads();
    {
        unsigned long long v0 = s_pk[t], v1 = s_pk[t + SBLK];
        if (v0) atomicAdd(&gpack[t], v0);
        if (v1) atomicAdd(&gpack[t + SBLK], v1);
    }
    // ---- last-block-done: run the group phase once all histograms merged ----
    __shared__ int s_last;
    __threadfence();
    __syncthreads();
    if (t == 0) s_last = (atomicAdd(done, 1u) == gridDim.x - 1) ? 1 : 0;
    __syncthreads();
    if (!s_last) return;

    // group phase (one block, SBLK threads, NGROUPS groups)
    __shared__ unsigned s_v[NGROUPS];
    __shared__ unsigned s_ps[SBLK];
    for (int g = t; g < NGROUPS; g += SBLK) {
        unsigned long long pk = atomicAdd(&gpack[g], 0ull);   // L2-coherent read
        unsigned c = (unsigned)(pk >> CNT_SHIFT);
        float S0 = (float)((double)(pk & SUM_MASK) * FIX_INV);
        float nf = (float)c;
        float L = 0.95f * nf;
        float U = 1.05f * nf;
        unsigned f = (S0 >= L && S0 <= U) ? 1u : 0u;
        feas[g] = f;
        gT[g]   = (S0 < L) ? L : U;
        gmn[g]  = 0xFFFFFFFFu;      // rare-path bracket accumulators
        gmx[g]  = 0u;
        s_v[g]  = f ? 0u : c;
    }
    __syncthreads();
    unsigned a0 = s_v[2 * t], a1 = s_v[2 * t + 1];
    unsigned ps = a0 + a1;
    s_ps[t] = ps;
    for (int off = 1; off < SBLK; off <<= 1) {
        __syncthreads();
        unsigned tmp = (t >= off) ? s_ps[t - off] : 0u;
        __syncthreads();
        s_ps[t] += tmp;
    }
    __syncthreads();
    unsigned incl = s_ps[t];
    unsigned b0 = incl - ps;
    gbase[2 * t]     = b0;      gcur[2 * t]     = b0;
    gbase[2 * t + 1] = b0 + a0; gcur[2 * t + 1] = b0 + a0;
    if (t == SBLK - 1) *total = incl;
}

// ---- kernel C (rare path): bracket min/max + index compaction, fused ----
__global__ __launch_bounds__(256) void k_mmc(const float4* __restrict__ yraw4,
                                             const float4* __restrict__ yreal4,
                                             const int4*   __restrict__ gid4,
                                             const unsigned* __restrict__ feas,
                                             unsigned* gcur, const unsigned* total,
                                             unsigned* gmn, unsigned* gmx,
                                             unsigned* cidx, unsigned* cgid,
                                             unsigned capacity, int n4) {
    if (*total == 0u) return;           // expected path: exit immediately
    __shared__ unsigned s_feas[NGROUPS];
    __shared__ unsigned s_mn[NGROUPS];
    __shared__ unsigned s_mx[NGROUPS];
    for (int g = threadIdx.x; g < NGROUPS; g += blockDim.x) {
        s_feas[g] = feas[g]; s_mn[g] = 0xFFFFFFFFu; s_mx[g] = 0u;
    }
    __syncthreads();
    int stride = gridDim.x * blockDim.x;
    for (int i = blockIdx.x * blockDim.x + threadIdx.x; i < n4; i += stride) {
        int4 gg = gid4[i];
        int gs[4] = { gg.x, gg.y, gg.z, gg.w };
        bool any = !s_feas[gs[0]] || !s_feas[gs[1]] || !s_feas[gs[2]] || !s_feas[gs[3]];
        if (!any) continue;
        float4 yr = yraw4[i];
        float4 ye = yreal4[i];
        float yrs[4] = { yr.x, yr.y, yr.z, yr.w };
        float yes[4] = { ye.x, ye.y, ye.z, ye.w };
#pragma unroll
        for (int j = 0; j < 4; ++j) {
            int g = gs[j];
            if (s_feas[g]) continue;
            float yraw = yrs[j];
            float yrc  = fmaxf(yes[j], EPSF);
            float l = 0.9f * yrc;
            float u = 1.1f * yrc;
            float w = 1.0f / yrc;
            float a0 = (l - yraw) * w;   // exact ref fp32 ops -> bitwise bracket
            float a1 = (u - yraw) * w;
            atomicMin(&s_mn[g], enc_f(a0));
            atomicMax(&s_mx[g], enc_f(a1));
            unsigned pos = atomicAdd(&gcur[g], 1u);
            if (pos < capacity) {
                cidx[pos] = (unsigned)(4 * i + j);
                cgid[pos] = (unsigned)g;
            }
        }
    }
    __syncthreads();
    for (int g = threadIdx.x; g < NGROUPS; g += blockDim.x) {
        if (!s_feas[g]) {
            atomicMin(&gmn[g], s_mn[g]);
            atomicMax(&gmx[g], s_mx[g]);
        }
    }
}

// ---- kernel D: per-group bisection + output fixup (one block per group) ----
#define CAPC 8064   // float2 cache: 64512 B
__global__ __launch_bounds__(256) void k_bisect(const float* __restrict__ y_raw,
                                                const float* __restrict__ y_real,
                                                const unsigned* feas,
                                                const unsigned long long* gpack,
                                                const unsigned* gbase, const float* gT,
                                                const unsigned* gmn, const unsigned* gmx,
                                                const unsigned* __restrict__ cidx,
                                                float* __restrict__ out,
                                                unsigned capacity) {
    int g = blockIdx.x;
    if (feas[g]) return;
    __shared__ float2 cache[CAPC];
    __shared__ double s_part[4];
    __shared__ float  s_mid;
    unsigned base = gbase[g];
    unsigned cnt  = (unsigned)(gpack[g] >> CNT_SHIFT);
    if (base >= capacity) cnt = 0;
    else if (cnt > capacity - base) cnt = capacity - base;
    int t = threadIdx.x;
    for (unsigned i = t; i < cnt && i < CAPC; i += 256u) {
        unsigned idx = cidx[base + i];
        cache[i] = make_float2(y_raw[idx], y_real[idx]);
    }
    __syncthreads();
    float lo = dec_f(gmn[g]) - 1.0f;     // ref: segment_min(...) - 1
    float hi = dec_f(gmx[g]) + 1.0f;     // ref: segment_max(...) + 1
    float T  = gT[g];
    for (int it = 0; it < MAX_ITERS; ++it) {
        if (t == 0) s_mid = 0.5f * (lo + hi);
        __syncthreads();
        float m = s_mid;
        double part = 0.0;
        for (unsigned i = t; i < cnt; i += 256u) {
            float yraw, ye;
            if (i < CAPC) { float2 v = cache[i]; yraw = v.x; ye = v.y; }
            else { unsigned idx = cidx[base + i]; yraw = y_raw[idx]; ye = y_real[idx]; }
            float yrc = fmaxf(ye, EPSF);
            float l = 0.9f * yrc;
            float u = 1.1f * yrc;
            float w = 1.0f / yrc;
            float ym = fminf(fmaxf(yraw + m / w, l), u);   // ref: clip(y_raw+mid/w,l,u)
            part += (double)(w * ym);
        }
#pragma unroll
        for (int off = 32; off > 0; off >>= 1) part += __shfl_down(part, off, 64);
        if ((t & 63) == 0) s_part[t >> 6] = part;
        __syncthreads();
        if (t == 0) {
            float Smid = (float)(s_part[0] + s_part[1] + s_part[2] + s_part[3]);
            if (Smid < T) lo = m; else hi = m;
        }
        __syncthreads();
    }
    // s_mid holds the LAST mid (ref returns last mid's y). Fused fixup:
    float m = s_mid;
    for (unsigned i = t; i < cnt; i += 256u) {
        unsigned idx = cidx[base + i];
        float yraw, ye;
        if (i < CAPC) { float2 v = cache[i]; yraw = v.x; ye = v.y; }
        else { yraw = y_raw[idx]; ye = y_real[idx]; }
        float yrc = fmaxf(ye, EPSF);
        float l = 0.9f * yrc;
        float u = 1.1f * yrc;
        float w = 1.0f / yrc;
        out[idx] = fminf(fmaxf(yraw + m / w, l), u);
    }
}

extern "C" void kernel_launch(void* const* d_in, const int* in_sizes, int n_in,
                              void* d_out, int out_size, void* d_ws, size_t ws_size,
                              hipStream_t stream) {
    const float* y_raw  = (const float*)d_in[0];
    const float* y_real = (const float*)d_in[1];
    const int*   gid    = (const int*)d_in[2];
    float* out = (float*)d_out;
    const int n  = in_sizes[0];      // 8388608
    const int n4 = n / 4;

    char* ws = (char*)d_ws;
    unsigned long long* gpack = (unsigned long long*)(ws + 0);       // 8 KB
    unsigned* gmn    = (unsigned*)(ws + 8192);
    unsigned* gmx    = (unsigned*)(ws + 12288);
    unsigned* feas   = (unsigned*)(ws + 16384);
    float*    gT     = (float*)(ws + 20480);
    unsigned* gbase  = (unsigned*)(ws + 24576);
    unsigned* gcur   = (unsigned*)(ws + 28672);
    unsigned* total  = (unsigned*)(ws + 32768);
    unsigned* done   = (unsigned*)(ws + 36864);
    unsigned* cidx   = (unsigned*)(ws + 40960);
    size_t cap64 = (ws_size > 40960) ? (ws_size - 40960) / 8 : 0;
    if (cap64 > (size_t)n) cap64 = (size_t)n;
    unsigned capacity = (unsigned)cap64;
    unsigned* cgid = cidx + capacity;

    const int per_blk = SBLK * STILE;                 // 2048 float4s / block
    k_init<<<1, NGROUPS, 0, stream>>>(gpack, done);
    if (n4 % per_blk == 0) {
        k_stats<true><<<n4 / per_blk, SBLK, 0, stream>>>(
            (const float4*)y_raw, (const float4*)y_real, (const int4*)gid,
            (float4*)out, gpack, done, feas, gT, gmn, gmx, gbase, gcur, total, n4);
    } else {
        k_stats<false><<<(n4 + per_blk - 1) / per_blk, SBLK, 0, stream>>>(
            (const float4*)y_raw, (const float4*)y_real, (const int4*)gid,
            (float4*)out, gpack, done, feas, gT, gmn, gmx, gbase, gcur, total, n4);
    }
    k_mmc<<<512, 256, 0, stream>>>((const float4*)y_raw, (const float4*)y_real,
                                   (const int4*)gid, feas, gcur, total,
                                   gmn, gmx, cidx, cgid, capacity, n4);
    k_bisect<<<NGROUPS, 256, 0, stream>>>(y_raw, y_real, feas, gpack, gbase, gT,
                                          gmn, gmx, cidx, out, capacity);
}

// Round 5
// 148.515 us; speedup vs baseline: 2.7628x; 2.7628x over previous
//
#include <hip/hip_runtime.h>

#define NGROUPS  1024
#define EPSF     1e-9f
#define MAX_ITERS 30
#define SUM_MASK ((1ull << 49) - 1)
#define CNT_SHIFT 49
#define FIX_SCALE 1073741824.0f      // 2^30
#define FIX_INV   (1.0 / 1073741824.0)
#define SBLK 512                     // k_stats block size
#define STILE 4                      // float4 tiles per thread

// ---- monotone float<->uint mapping for atomicMin/Max on floats ----
__device__ __forceinline__ unsigned enc_f(float f) {
    unsigned u = __float_as_uint(f);
    return (u & 0x80000000u) ? ~u : (u | 0x80000000u);
}
__device__ __forceinline__ float dec_f(unsigned e) {
    unsigned u = (e & 0x80000000u) ? (e ^ 0x80000000u) : ~e;
    return __uint_as_float(u);
}

// ---- kernel 0: init gpack (ws poisoned 0xAA each launch) ----
__global__ __launch_bounds__(NGROUPS) void k_init(unsigned long long* gpack) {
    gpack[threadIdx.x] = 0ull;
}

// ---- kernel A: stream once; write y_clipped; packed (cnt|sum) LDS histogram ----
// launch_bounds(512, 2): VGPR cap 256 so all 12 loads can be hoisted in flight.
template <bool EXACT>
__global__ __launch_bounds__(SBLK, 2) void k_stats(const float4* __restrict__ yraw4,
                                                   const float4* __restrict__ yreal4,
                                                   const int4*   __restrict__ gid4,
                                                   float4*       __restrict__ out4,
                                                   unsigned long long* gpack, int n4) {
    __shared__ unsigned long long s_pk[NGROUPS];
    int t = threadIdx.x;
    s_pk[t] = 0ull; s_pk[t + SBLK] = 0ull;
    __syncthreads();

    int base = blockIdx.x * (SBLK * STILE) + t;
    if (EXACT) {
        float4 yr[STILE], ye[STILE];
        int4   gg[STILE];
        // unconditional loads -> all 12 issued before any use (MLP)
#pragma unroll
        for (int k = 0; k < STILE; ++k) yr[k] = yraw4[base + k * SBLK];
#pragma unroll
        for (int k = 0; k < STILE; ++k) ye[k] = yreal4[base + k * SBLK];
#pragma unroll
        for (int k = 0; k < STILE; ++k) gg[k] = gid4[base + k * SBLK];
#pragma unroll
        for (int k = 0; k < STILE; ++k) {
            float yrs[4] = { yr[k].x, yr[k].y, yr[k].z, yr[k].w };
            float yes[4] = { ye[k].x, ye[k].y, ye[k].z, ye[k].w };
            int   gs[4]  = { gg[k].x, gg[k].y, gg[k].z, gg[k].w };
            float oc[4];
#pragma unroll
            for (int j = 0; j < 4; ++j) {
                float yraw = yrs[j];
                float yrc  = fmaxf(yes[j], EPSF);
                float l = 0.9f * yrc;
                float u = 1.1f * yrc;
                float yclip = fminf(fmaxf(yraw, l), u);
                oc[j] = yclip;
                float s = yclip / yrc;                    // in [0.9, 1.1]
                unsigned long long pk = (1ull << CNT_SHIFT)
                    + (unsigned long long)__float2uint_rn(s * FIX_SCALE);
                atomicAdd(&s_pk[gs[j]], pk);
            }
            out4[base + k * SBLK] = make_float4(oc[0], oc[1], oc[2], oc[3]);
        }
    } else {
#pragma unroll
        for (int k = 0; k < STILE; ++k) {
            int i = base + k * SBLK;
            if (i >= n4) continue;
            float4 a = yraw4[i], b = yreal4[i];
            int4 g4 = gid4[i];
            float yrs[4] = { a.x, a.y, a.z, a.w };
            float yes[4] = { b.x, b.y, b.z, b.w };
            int   gs[4]  = { g4.x, g4.y, g4.z, g4.w };
            float oc[4];
#pragma unroll
            for (int j = 0; j < 4; ++j) {
                float yrc  = fmaxf(yes[j], EPSF);
                float l = 0.9f * yrc, u = 1.1f * yrc;
                float yclip = fminf(fmaxf(yrs[j], l), u);
                oc[j] = yclip;
                unsigned long long pk = (1ull << CNT_SHIFT)
                    + (unsigned long long)__float2uint_rn((yclip / yrc) * FIX_SCALE);
                atomicAdd(&s_pk[gs[j]], pk);
            }
            out4[i] = make_float4(oc[0], oc[1], oc[2], oc[3]);
        }
    }
    __syncthreads();
    unsigned long long v0 = s_pk[t], v1 = s_pk[t + SBLK];
    if (v0) atomicAdd(&gpack[t], v0);
    if (v1) atomicAdd(&gpack[t + SBLK], v1);
}

// ---- kernel B: per-group scalars (feasible, T) + compaction offsets ----
__global__ __launch_bounds__(NGROUPS) void k_group(const unsigned long long* gpack,
                                                   unsigned* feas, float* gT,
                                                   unsigned* gmn, unsigned* gmx,
                                                   unsigned* gbase, unsigned* gcur,
                                                   unsigned* total) {
    __shared__ unsigned s_scan[NGROUPS];
    int g = threadIdx.x;
    unsigned long long pk = gpack[g];
    unsigned c = (unsigned)(pk >> CNT_SHIFT);
    float S0 = (float)((double)(pk & SUM_MASK) * FIX_INV);
    float nf = (float)c;
    float L = 0.95f * nf;
    float U = 1.05f * nf;
    unsigned f = (S0 >= L && S0 <= U) ? 1u : 0u;
    feas[g] = f;
    gT[g]   = (S0 < L) ? L : U;
    gmn[g]  = 0xFFFFFFFFu;      // rare-path bracket accumulators
    gmx[g]  = 0u;

    unsigned v = f ? 0u : c;
    s_scan[g] = v;
    for (int off = 1; off < NGROUPS; off <<= 1) {
        __syncthreads();
        unsigned tmp = (g >= off) ? s_scan[g - off] : 0u;
        __syncthreads();
        s_scan[g] += tmp;
    }
    __syncthreads();
    unsigned incl = s_scan[g];
    unsigned base = incl - v;
    gbase[g] = base;
    gcur[g]  = base;
    if (g == NGROUPS - 1) *total = incl;
}

// ---- kernel C (rare path): bracket min/max + index compaction, fused ----
__global__ __launch_bounds__(256) void k_mmc(const float4* __restrict__ yraw4,
                                             const float4* __restrict__ yreal4,
                                             const int4*   __restrict__ gid4,
                                             const unsigned* __restrict__ feas,
                                             unsigned* gcur, const unsigned* total,
                                             unsigned* gmn, unsigned* gmx,
                                             unsigned* cidx, unsigned* cgid,
                                             unsigned capacity, int n4) {
    if (*total == 0u) return;           // expected path: exit immediately
    __shared__ unsigned s_feas[NGROUPS];
    __shared__ unsigned s_mn[NGROUPS];
    __shared__ unsigned s_mx[NGROUPS];
    for (int g = threadIdx.x; g < NGROUPS; g += blockDim.x) {
        s_feas[g] = feas[g]; s_mn[g] = 0xFFFFFFFFu; s_mx[g] = 0u;
    }
    __syncthreads();
    int stride = gridDim.x * blockDim.x;
    for (int i = blockIdx.x * blockDim.x + threadIdx.x; i < n4; i += stride) {
        int4 gg = gid4[i];
        int gs[4] = { gg.x, gg.y, gg.z, gg.w };
        bool any = !s_feas[gs[0]] || !s_feas[gs[1]] || !s_feas[gs[2]] || !s_feas[gs[3]];
        if (!any) continue;
        float4 yr = yraw4[i];
        float4 ye = yreal4[i];
        float yrs[4] = { yr.x, yr.y, yr.z, yr.w };
        float yes[4] = { ye.x, ye.y, ye.z, ye.w };
#pragma unroll
        for (int j = 0; j < 4; ++j) {
            int g = gs[j];
            if (s_feas[g]) continue;
            float yraw = yrs[j];
            float yrc  = fmaxf(yes[j], EPSF);
            float l = 0.9f * yrc;
            float u = 1.1f * yrc;
            float w = 1.0f / yrc;
            float a0 = (l - yraw) * w;   // exact ref fp32 ops -> bitwise bracket
            float a1 = (u - yraw) * w;
            atomicMin(&s_mn[g], enc_f(a0));
            atomicMax(&s_mx[g], enc_f(a1));
            unsigned pos = atomicAdd(&gcur[g], 1u);
            if (pos < capacity) {
                cidx[pos] = (unsigned)(4 * i + j);
                cgid[pos] = (unsigned)g;
            }
        }
    }
    __syncthreads();
    for (int g = threadIdx.x; g < NGROUPS; g += blockDim.x) {
        if (!s_feas[g]) {
            atomicMin(&gmn[g], s_mn[g]);
            atomicMax(&gmx[g], s_mx[g]);
        }
    }
}

// ---- kernel D: per-group bisection + output fixup (one block per group) ----
#define CAPC 8064   // float2 cache: 64512 B
__global__ __launch_bounds__(256) void k_bisect(const float* __restrict__ y_raw,
                                                const float* __restrict__ y_real,
                                                const unsigned* feas,
                                                const unsigned long long* gpack,
                                                const unsigned* gbase, const float* gT,
                                                const unsigned* gmn, const unsigned* gmx,
                                                const unsigned* __restrict__ cidx,
                                                float* __restrict__ out,
                                                unsigned capacity) {
    int g = blockIdx.x;
    if (feas[g]) return;
    __shared__ float2 cache[CAPC];
    __shared__ double s_part[4];
    __shared__ float  s_mid;
    unsigned base = gbase[g];
    unsigned cnt  = (unsigned)(gpack[g] >> CNT_SHIFT);
    if (base >= capacity) cnt = 0;
    else if (cnt > capacity - base) cnt = capacity - base;
    int t = threadIdx.x;
    for (unsigned i = t; i < cnt && i < CAPC; i += 256u) {
        unsigned idx = cidx[base + i];
        cache[i] = make_float2(y_raw[idx], y_real[idx]);
    }
    __syncthreads();
    float lo = dec_f(gmn[g]) - 1.0f;     // ref: segment_min(...) - 1
    float hi = dec_f(gmx[g]) + 1.0f;     // ref: segment_max(...) + 1
    float T  = gT[g];
    for (int it = 0; it < MAX_ITERS; ++it) {
        if (t == 0) s_mid = 0.5f * (lo + hi);
        __syncthreads();
        float m = s_mid;
        double part = 0.0;
        for (unsigned i = t; i < cnt; i += 256u) {
            float yraw, ye;
            if (i < CAPC) { float2 v = cache[i]; yraw = v.x; ye = v.y; }
            else { unsigned idx = cidx[base + i]; yraw = y_raw[idx]; ye = y_real[idx]; }
            float yrc = fmaxf(ye, EPSF);
            float l = 0.9f * yrc;
            float u = 1.1f * yrc;
            float w = 1.0f / yrc;
            float ym = fminf(fmaxf(yraw + m / w, l), u);   // ref: clip(y_raw+mid/w,l,u)
            part += (double)(w * ym);
        }
#pragma unroll
        for (int off = 32; off > 0; off >>= 1) part += __shfl_down(part, off, 64);
        if ((t & 63) == 0) s_part[t >> 6] = part;
        __syncthreads();
        if (t == 0) {
            float Smid = (float)(s_part[0] + s_part[1] + s_part[2] + s_part[3]);
            if (Smid < T) lo = m; else hi = m;
        }
        __syncthreads();
    }
    // s_mid holds the LAST mid (ref returns last mid's y). Fused fixup:
    float m = s_mid;
    for (unsigned i = t; i < cnt; i += 256u) {
        unsigned idx = cidx[base + i];
        float yraw, ye;
        if (i < CAPC) { float2 v = cache[i]; yraw = v.x; ye = v.y; }
        else { yraw = y_raw[idx]; ye = y_real[idx]; }
        float yrc = fmaxf(ye, EPSF);
        float l = 0.9f * yrc;
        float u = 1.1f * yrc;
        float w = 1.0f / yrc;
        out[idx] = fminf(fmaxf(yraw + m / w, l), u);
    }
}

extern "C" void kernel_launch(void* const* d_in, const int* in_sizes, int n_in,
                              void* d_out, int out_size, void* d_ws, size_t ws_size,
                              hipStream_t stream) {
    const float* y_raw  = (const float*)d_in[0];
    const float* y_real = (const float*)d_in[1];
    const int*   gid    = (const int*)d_in[2];
    float* out = (float*)d_out;
    const int n  = in_sizes[0];      // 8388608
    const int n4 = n / 4;

    char* ws = (char*)d_ws;
    unsigned long long* gpack = (unsigned long long*)(ws + 0);       // 8 KB
    unsigned* gmn    = (unsigned*)(ws + 8192);
    unsigned* gmx    = (unsigned*)(ws + 12288);
    unsigned* feas   = (unsigned*)(ws + 16384);
    float*    gT     = (float*)(ws + 20480);
    unsigned* gbase  = (unsigned*)(ws + 24576);
    unsigned* gcur   = (unsigned*)(ws + 28672);
    unsigned* total  = (unsigned*)(ws + 32768);
    unsigned* cidx   = (unsigned*)(ws + 40960);
    size_t cap64 = (ws_size > 40960) ? (ws_size - 40960) / 8 : 0;
    if (cap64 > (size_t)n) cap64 = (size_t)n;
    unsigned capacity = (unsigned)cap64;
    unsigned* cgid = cidx + capacity;

    const int per_blk = SBLK * STILE;                 // 2048 float4s / block
    k_init<<<1, NGROUPS, 0, stream>>>(gpack);
    if (n4 % per_blk == 0) {
        k_stats<true><<<n4 / per_blk, SBLK, 0, stream>>>(
            (const float4*)y_raw, (const float4*)y_real, (const int4*)gid,
            (float4*)out, gpack, n4);
    } else {
        k_stats<false><<<(n4 + per_blk - 1) / per_blk, SBLK, 0, stream>>>(
            (const float4*)y_raw, (const float4*)y_real, (const int4*)gid,
            (float4*)out, gpack, n4);
    }
    k_group<<<1, NGROUPS, 0, stream>>>(gpack, feas, gT, gmn, gmx, gbase, gcur, total);
    k_mmc<<<512, 256, 0, stream>>>((const float4*)y_raw, (const float4*)y_real,
                                   (const int4*)gid, feas, gcur, total,
                                   gmn, gmx, cidx, cgid, capacity, n4);
    k_bisect<<<NGROUPS, 256, 0, stream>>>(y_raw, y_real, feas, gpack, gbase, gT,
                                          gmn, gmx, cidx, out, capacity);
}